// Round 9
// baseline (56.295 us; speedup 1.0000x reference)
//
#include <hip/hip_runtime.h>
#include <hip/hip_fp16.h>

#define CROP_H 14
#define CROP_W 14
#define CROP_HW 196
#define CROP_HWP 98          // pairs per box
#define IMG_H 100
#define IMG_W 100
#define PLANE 10000
#define NCH 256
#define NBOX 512
#define NIMG 8

// d_ws layout:
//   geo_sorted : uint2[NBOX*CROP_HW]  (8 B per (slot,hw), sorted by image) @ 0
//   slot_of    : int[NBOX]                                                 @ GEO_BYTES
//   starts     : int[NIMG+1]                                               @ GEO_BYTES + NBOX*4
#define GEO_BYTES ((size_t)NBOX * CROP_HW * 8)
#define WS_NEED   (GEO_BYTES + NBOX * 4 + (NIMG + 1) * 4)

// ---------------- Kernel 1: stable bucket scan -> slot_of / starts ----------------
__global__ __launch_bounds__(64) void perm_kernel(
    const int* __restrict__ box_ind, int* __restrict__ slot_of, int* __restrict__ starts)
{
    const int t = threadIdx.x;
    int base = 0;
    for (int b = 0; b < NIMG; ++b) {
        if (t == 0) starts[b] = base;
        int nb = 0;
        for (int k = 0; k < NBOX / 64; ++k) {
            const int n = k * 64 + t;
            const bool m = (box_ind[n] == b);
            const unsigned long long mask = __ballot(m);
            if (m) slot_of[n] = base + nb + __popcll(mask & ((1ull << t) - 1ull));
            nb += __popcll(mask);
        }
        base += nb;   // uniform across lanes
    }
    if (t == 0) starts[NIMG] = base;
}

// ---------------- Kernel 2: geometry, written pre-sorted with n embedded ----------
// pk bits: [13:0]=tl slot (y0*100+x0), [15]=dy, [16]=valid, [25:17]=n
// (dx clamp is absorbed by the shifted-pair LDS layout in the main kernel)
__global__ __launch_bounds__(256) void geom_kernel(
    const float* __restrict__ boxes, const int* __restrict__ slot_of,
    uint2* __restrict__ geo)
{
    const int n = blockIdx.x;
    const int t = threadIdx.x;
    if (t >= CROP_HW) return;
    const int h = t / CROP_W;
    const int w = t - h * CROP_W;

    const float4 bx = reinterpret_cast<const float4*>(boxes)[n];
    const float y1 = bx.x, x1 = bx.y, y2 = bx.z, x2 = bx.w;

    const float scale_y = (y2 - y1) * (float)(IMG_H - 1) / (float)(CROP_H - 1);
    const float scale_x = (x2 - x1) * (float)(IMG_W - 1) / (float)(CROP_W - 1);

    const float in_y = y1 * (float)(IMG_H - 1) + (float)h * scale_y;
    const float in_x = x1 * (float)(IMG_W - 1) + (float)w * scale_x;

    const bool valid = (in_y >= 0.0f) & (in_y <= (float)(IMG_H - 1)) &
                       (in_x >= 0.0f) & (in_x <= (float)(IMG_W - 1));

    const float yc = fminf(fmaxf(in_y, 0.0f), (float)(IMG_H - 1));
    const float xc = fminf(fmaxf(in_x, 0.0f), (float)(IMG_W - 1));

    const float y0f = floorf(yc);
    const float x0f = floorf(xc);
    const float ly = yc - y0f;
    const float lx = xc - x0f;

    const int y0  = (int)y0f;
    const int x0  = (int)x0f;
    const int dy  = min(y0 + 1, IMG_H - 1) - y0;   // 0/1

    const unsigned pk = (unsigned)(y0 * IMG_W + x0)
                      | ((unsigned)dy << 15)
                      | (valid ? (1u << 16) : 0u) | ((unsigned)n << 17);

    const __half2 hh = __floats2half2_rn(lx, ly);
    const unsigned hbits = *reinterpret_cast<const unsigned*>(&hh);

    const int slot = slot_of[n];
    geo[slot * CROP_HW + t] = make_uint2(pk, hbits);
}

// ---------------- bilinear from fp16 shifted-pair LDS plane ----------------
// sp[o] = half2{ p[o], p[o+1 clamped] }  (4 B/slot -> bank = o % 32, 2-way max)
__device__ __forceinline__ float bilerp_h2(const __half2* __restrict__ sp,
                                           unsigned pk, unsigned hbits)
{
    const int o   = (int)(pk & 0x3FFFu);
    const int dyo = (int)((pk >> 15) & 1u) * IMG_W;
    const __half2 h = *reinterpret_cast<const __half2*>(&hbits);
    const float lx = __low2float(h);
    const float ly = __high2float(h);
    const float wm = (pk & (1u << 16)) ? 1.0f : 0.0f;

    const __half2 tp = sp[o];           // {tl, tr}
    const __half2 bp = sp[o + dyo];     // {bl, br}

    const float tl = __low2float(tp), tr = __high2float(tp);
    const float bl = __low2float(bp), br = __high2float(bp);

    const float top = tl + (tr - tl) * lx;
    const float bot = bl + (br - bl) * lx;
    return (top + (bot - top) * ly) * wm;
}

// ---------------- Kernel 3: one block per (b,c) plane; 512 thr; 4 blk/CU ----------
__global__ __launch_bounds__(512, 6) void crop_resize_main(
    const float* __restrict__ image,    // (8, 256, 100, 100)
    const int*   __restrict__ starts,   // [9]
    const uint2* __restrict__ geo,      // sorted, n embedded
    float* __restrict__ out)            // (512, 256, 14, 14)
{
    __shared__ __half2 s_pairs[PLANE];  // 40000 B: slot x = {p[x], p[x+1 clamped]}

    const int blk = blockIdx.x;
    const int b   = blk >> 8;
    const int c   = blk & 255;
    const int t   = threadIdx.x;

    const float* __restrict__ plane =
        image + ((size_t)(b * NCH + c)) * PLANE;
    const float4* __restrict__ plane_g = reinterpret_cast<const float4*>(plane);

    // stage shifted fp16 pairs: 2500 float4 groups -> 4 slots each
    for (int i = t; i < PLANE / 4; i += 512) {
        const float4 f = plane_g[i];
        const int m    = i % (IMG_W / 4);            // 25 groups per row
        const int base = 4 * i;
        // last group of a row: slot base+3 = {p[99], p[99]} (x-edge clamp)
        const float nx = plane[base + ((m == (IMG_W / 4 - 1)) ? 3 : 4)];
        s_pairs[base + 0] = __floats2half2_rn(f.x, f.y);
        s_pairs[base + 1] = __floats2half2_rn(f.y, f.z);
        s_pairs[base + 2] = __floats2half2_rn(f.z, f.w);
        s_pairs[base + 3] = __floats2half2_rn(f.w, nx);
    }

    const int sb     = starts[b];
    const int totalp = (starts[b + 1] - sb) * CROP_HWP;   // pair units
    __syncthreads();

    const uint4* __restrict__ geo4 =
        reinterpret_cast<const uint4*>(geo) + (size_t)sb * CROP_HWP;
    float* __restrict__ outc = out + (size_t)c * CROP_HW;

    int p0 = t;
    int p1 = t + 512;
    bool h0 = p0 < totalp;
    bool h1 = p1 < totalp;
    uint4 g0, g1;
    if (h0) g0 = geo4[p0];
    if (h1) g1 = geo4[p1];

    while (h0) {
        // prefetch next unrolled pair of geo entries
        const int pn0 = p0 + 1024;
        const int pn1 = p1 + 1024;
        const bool hn0 = pn0 < totalp;
        const bool hn1 = pn1 < totalp;
        uint4 gn0, gn1;
        if (hn0) gn0 = geo4[pn0];
        if (hn1) gn1 = geo4[pn1];

        // entry 0 (always valid here)
        {
            const unsigned n = g0.x >> 17;
            const int hw = (p0 % CROP_HWP) * 2;
            const float v0 = bilerp_h2(s_pairs, g0.x, g0.y);
            const float v1 = bilerp_h2(s_pairs, g0.z, g0.w);
            const float2 val = make_float2(v0, v1);
            unsigned long long bits = __builtin_bit_cast(unsigned long long, val);
            __builtin_nontemporal_store(bits,
                reinterpret_cast<unsigned long long*>(
                    outc + (size_t)n * (NCH * CROP_HW) + hw));
        }
        // entry 1
        if (h1) {
            const unsigned n = g1.x >> 17;
            const int hw = (p1 % CROP_HWP) * 2;
            const float v0 = bilerp_h2(s_pairs, g1.x, g1.y);
            const float v1 = bilerp_h2(s_pairs, g1.z, g1.w);
            const float2 val = make_float2(v0, v1);
            unsigned long long bits = __builtin_bit_cast(unsigned long long, val);
            __builtin_nontemporal_store(bits,
                reinterpret_cast<unsigned long long*>(
                    outc + (size_t)n * (NCH * CROP_HW) + hw));
        }

        p0 = pn0; p1 = pn1;
        h0 = hn0; h1 = hn1;
        g0 = gn0; g1 = gn1;
    }
}

// ---------------- Fallback (ws too small): known-good direct kernel ----------------
__global__ __launch_bounds__(256) void crop_resize_simple(
    const float* __restrict__ image, const float* __restrict__ boxes,
    const int* __restrict__ box_ind, float* __restrict__ out)
{
    const int n = blockIdx.y;
    const int i = blockIdx.x * 256 + threadIdx.x;
    const int c  = i / CROP_HW;
    const int hw = i - c * CROP_HW;
    const int h  = hw / CROP_W;
    const int w  = hw - h * CROP_W;

    const float y1 = boxes[n * 4 + 0];
    const float x1 = boxes[n * 4 + 1];
    const float y2 = boxes[n * 4 + 2];
    const float x2 = boxes[n * 4 + 3];
    const int   b  = box_ind[n];

    const float scale_y = (y2 - y1) * (float)(IMG_H - 1) / (float)(CROP_H - 1);
    const float scale_x = (x2 - x1) * (float)(IMG_W - 1) / (float)(CROP_W - 1);
    const float in_y = y1 * (float)(IMG_H - 1) + (float)h * scale_y;
    const float in_x = x1 * (float)(IMG_W - 1) + (float)w * scale_x;
    const bool valid = (in_y >= 0.0f) & (in_y <= (float)(IMG_H - 1)) &
                       (in_x >= 0.0f) & (in_x <= (float)(IMG_W - 1));
    const float yc = fminf(fmaxf(in_y, 0.0f), (float)(IMG_H - 1));
    const float xc = fminf(fmaxf(in_x, 0.0f), (float)(IMG_W - 1));
    const float y0f = floorf(yc), x0f = floorf(xc);
    const float ly = yc - y0f, lx = xc - x0f;
    const int y0 = (int)y0f, x0 = (int)x0f;
    const int y1i = min(y0 + 1, IMG_H - 1), x1i = min(x0 + 1, IMG_W - 1);

    const float* __restrict__ p = image + ((size_t)(b * NCH + c)) * PLANE;
    const float tl = p[y0  * IMG_W + x0];
    const float tr = p[y0  * IMG_W + x1i];
    const float bl = p[y1i * IMG_W + x0];
    const float br = p[y1i * IMG_W + x1i];
    const float top = tl + (tr - tl) * lx;
    const float bot = bl + (br - bl) * lx;
    float val = top + (bot - top) * ly;
    out[(size_t)n * (NCH * CROP_HW) + i] = valid ? val : 0.0f;
}

extern "C" void kernel_launch(void* const* d_in, const int* in_sizes, int n_in,
                              void* d_out, int out_size, void* d_ws, size_t ws_size,
                              hipStream_t stream) {
    const float* image   = (const float*)d_in[0];
    const float* boxes   = (const float*)d_in[1];
    const int*   box_ind = (const int*)d_in[2];
    float* out = (float*)d_out;

    if (ws_size < WS_NEED) {
        dim3 grid(196, NBOX);
        crop_resize_simple<<<grid, dim3(256), 0, stream>>>(image, boxes, box_ind, out);
        return;
    }

    uint2* geo    = (uint2*)d_ws;
    int*   slot_of = (int*)((char*)d_ws + GEO_BYTES);
    int*   starts  = slot_of + NBOX;

    perm_kernel<<<dim3(1), dim3(64), 0, stream>>>(box_ind, slot_of, starts);
    geom_kernel<<<dim3(NBOX), dim3(256), 0, stream>>>(boxes, slot_of, geo);
    crop_resize_main<<<dim3(NIMG * NCH), dim3(512), 0, stream>>>(image, starts, geo, out);
}

// Round 10
// 44.451 us; speedup vs baseline: 1.2665x; 1.2665x over previous
//
#include <hip/hip_runtime.h>
#include <hip/hip_fp16.h>

#define CROP_H 14
#define CROP_W 14
#define CROP_HW 196
#define CROP_HWP 98          // pair units per box
#define CROP_HWQ 49          // quad units per box
#define IMG_H 100
#define IMG_W 100
#define PLANE 10000
#define NCH 256
#define NBOX 512
#define NIMG 8

// d_ws layout: geo_sorted : uint2[NBOX*CROP_HW] (8 B per (slot,hw), sorted by image)
#define GEO_BYTES ((size_t)NBOX * CROP_HW * 8)
#define WS_NEED   GEO_BYTES

// ---------------- Kernel 1: geometry, self-computed stable slot, n embedded ------
// pk bits: [13:0]=tl slot (y0*100+x0), [15]=dy, [16]=valid, [25:17]=n
// (dx clamp absorbed by shifted-pair LDS layout in the main kernel)
__global__ __launch_bounds__(256) void geom_kernel(
    const float* __restrict__ boxes, const int* __restrict__ box_ind,
    uint2* __restrict__ geo)
{
    __shared__ int s_lt[8], s_eq[8];

    const int n    = blockIdx.x;
    const int t    = threadIdx.x;
    const int lane = t & 63;
    const int wv   = t >> 6;                 // 0..3
    const int bn   = box_ind[n];

    // stable bucket rank: slot = #{m: b[m]<bn} + #{m<n: b[m]==bn}
    #pragma unroll
    for (int r = 0; r < 2; ++r) {
        const int m  = r * 256 + t;          // covers 0..511
        const int bm = box_ind[m];
        const unsigned long long lt = __ballot(bm < bn);
        const unsigned long long eq = __ballot(bm == bn);
        const int rel = n - (r * 256 + wv * 64);
        const unsigned long long pre =
            (rel <= 0) ? 0ull : ((rel >= 64) ? ~0ull : ((1ull << rel) - 1ull));
        if (lane == 0) {
            s_lt[wv * 2 + r] = __popcll(lt);
            s_eq[wv * 2 + r] = __popcll(eq & pre);
        }
    }
    __syncthreads();
    int slot = 0;
    #pragma unroll
    for (int i = 0; i < 8; ++i) slot += s_lt[i] + s_eq[i];

    if (t >= CROP_HW) return;
    const int h = t / CROP_W;
    const int w = t - h * CROP_W;

    const float4 bx = reinterpret_cast<const float4*>(boxes)[n];
    const float y1 = bx.x, x1 = bx.y, y2 = bx.z, x2 = bx.w;

    const float scale_y = (y2 - y1) * (float)(IMG_H - 1) / (float)(CROP_H - 1);
    const float scale_x = (x2 - x1) * (float)(IMG_W - 1) / (float)(CROP_W - 1);

    const float in_y = y1 * (float)(IMG_H - 1) + (float)h * scale_y;
    const float in_x = x1 * (float)(IMG_W - 1) + (float)w * scale_x;

    const bool valid = (in_y >= 0.0f) & (in_y <= (float)(IMG_H - 1)) &
                       (in_x >= 0.0f) & (in_x <= (float)(IMG_W - 1));

    const float yc = fminf(fmaxf(in_y, 0.0f), (float)(IMG_H - 1));
    const float xc = fminf(fmaxf(in_x, 0.0f), (float)(IMG_W - 1));

    const float y0f = floorf(yc);
    const float x0f = floorf(xc);
    const float ly = yc - y0f;
    const float lx = xc - x0f;

    const int y0  = (int)y0f;
    const int x0  = (int)x0f;
    const int dy  = min(y0 + 1, IMG_H - 1) - y0;   // 0/1

    const unsigned pk = (unsigned)(y0 * IMG_W + x0)
                      | ((unsigned)dy << 15)
                      | (valid ? (1u << 16) : 0u) | ((unsigned)n << 17);

    const __half2 hh = __floats2half2_rn(lx, ly);
    const unsigned hbits = *reinterpret_cast<const unsigned*>(&hh);

    geo[slot * CROP_HW + t] = make_uint2(pk, hbits);
}

// ---------------- bilinear from fp16 shifted-pair LDS plane ----------------
// sp[o] = half2{ p[o], p[o+1 clamped] }  (4 B/slot -> bank = o % 32, 2-way max)
__device__ __forceinline__ float bilerp_h2(const __half2* __restrict__ sp,
                                           unsigned pk, unsigned hbits)
{
    const int o   = (int)(pk & 0x3FFFu);
    const int dyo = (int)((pk >> 15) & 1u) * IMG_W;
    const __half2 h = *reinterpret_cast<const __half2*>(&hbits);
    const float lx = __low2float(h);
    const float ly = __high2float(h);
    const float wm = (pk & (1u << 16)) ? 1.0f : 0.0f;

    const __half2 tp = sp[o];           // {tl, tr}
    const __half2 bp = sp[o + dyo];     // {bl, br}

    const float tl = __low2float(tp), tr = __high2float(tp);
    const float bl = __low2float(bp), br = __high2float(bp);

    const float top = tl + (tr - tl) * lx;
    const float bot = bl + (br - bl) * lx;
    return (top + (bot - top) * ly) * wm;
}

// ---------------- Kernel 2: one block per (b,c) plane; 512 thr; 4 blk/CU ----------
__global__ __launch_bounds__(512, 4) void crop_resize_main(
    const float* __restrict__ image,    // (8, 256, 100, 100)
    const int*   __restrict__ box_ind,  // (512,)
    const uint2* __restrict__ geo,      // sorted by image, n embedded
    float* __restrict__ out)            // (512, 256, 14, 14)
{
    __shared__ __half2 s_pairs[PLANE];  // 40000 B: slot x = {p[x], p[x+1 clamped]}
    __shared__ int s_ltm[8], s_eqm[8];

    const int blk = blockIdx.x;
    const int b   = blk >> 8;
    const int c   = blk & 255;
    const int t   = threadIdx.x;
    const int lane = t & 63;
    const int wv   = t >> 6;            // 0..7

    // self-computed bucket start/count: sb = #{m: b[m]<b}, nb = #{m: b[m]==b}
    {
        const int bm = box_ind[t];      // t covers all 512 boxes
        const unsigned long long lt = __ballot(bm < b);
        const unsigned long long eq = __ballot(bm == b);
        if (lane == 0) { s_ltm[wv] = __popcll(lt); s_eqm[wv] = __popcll(eq); }
    }

    const float* __restrict__ plane =
        image + ((size_t)(b * NCH + c)) * PLANE;
    const float4* __restrict__ plane_g = reinterpret_cast<const float4*>(plane);

    // stage shifted fp16 pairs: 2500 float4 groups -> 4 slots each
    for (int i = t; i < PLANE / 4; i += 512) {
        const float4 f = plane_g[i];
        const int m    = i % (IMG_W / 4);            // 25 groups per row
        const int base = 4 * i;
        // last group of a row: slot base+3 = {p[99], p[99]} (x-edge clamp)
        const float nx = plane[base + ((m == (IMG_W / 4 - 1)) ? 3 : 4)];
        s_pairs[base + 0] = __floats2half2_rn(f.x, f.y);
        s_pairs[base + 1] = __floats2half2_rn(f.y, f.z);
        s_pairs[base + 2] = __floats2half2_rn(f.z, f.w);
        s_pairs[base + 3] = __floats2half2_rn(f.w, nx);
    }
    __syncthreads();

    int sb = 0, nb = 0;
    #pragma unroll
    for (int i = 0; i < 8; ++i) { sb += s_ltm[i]; nb += s_eqm[i]; }

    const int totalq = nb * CROP_HWQ;   // quad units
    if (totalq == 0) return;

    const uint4* __restrict__ geo4 =
        reinterpret_cast<const uint4*>(geo) + (size_t)sb * CROP_HWP;
    float* __restrict__ outc = out + (size_t)c * CROP_HW;

    // branchless wrap-around loop: duplicate quads write identical bytes (benign)
    int q = t;
    while (q >= totalq) q -= totalq;
    uint4 ga = geo4[2 * q];
    uint4 gb = geo4[2 * q + 1];

    const int iters = (totalq + 511) >> 9;
    for (int it = 0; it < iters; ++it) {
        int qn = q + 512;
        while (qn >= totalq) qn -= totalq;
        const uint4 gna = geo4[2 * qn];       // unconditional prefetch
        const uint4 gnb = geo4[2 * qn + 1];

        const unsigned n = ga.x >> 17;
        const int j = q - (q / CROP_HWQ) * CROP_HWQ;

        float4 val;
        val.x = bilerp_h2(s_pairs, ga.x, ga.y);
        val.y = bilerp_h2(s_pairs, ga.z, ga.w);
        val.z = bilerp_h2(s_pairs, gb.x, gb.y);
        val.w = bilerp_h2(s_pairs, gb.z, gb.w);

        *reinterpret_cast<float4*>(outc + (size_t)n * (NCH * CROP_HW) + j * 4) = val;

        q = qn; ga = gna; gb = gnb;
    }
}

// ---------------- Fallback (ws too small): known-good direct kernel ----------------
__global__ __launch_bounds__(256) void crop_resize_simple(
    const float* __restrict__ image, const float* __restrict__ boxes,
    const int* __restrict__ box_ind, float* __restrict__ out)
{
    const int n = blockIdx.y;
    const int i = blockIdx.x * 256 + threadIdx.x;
    const int c  = i / CROP_HW;
    const int hw = i - c * CROP_HW;
    const int h  = hw / CROP_W;
    const int w  = hw - h * CROP_W;

    const float y1 = boxes[n * 4 + 0];
    const float x1 = boxes[n * 4 + 1];
    const float y2 = boxes[n * 4 + 2];
    const float x2 = boxes[n * 4 + 3];
    const int   b  = box_ind[n];

    const float scale_y = (y2 - y1) * (float)(IMG_H - 1) / (float)(CROP_H - 1);
    const float scale_x = (x2 - x1) * (float)(IMG_W - 1) / (float)(CROP_W - 1);
    const float in_y = y1 * (float)(IMG_H - 1) + (float)h * scale_y;
    const float in_x = x1 * (float)(IMG_W - 1) + (float)w * scale_x;
    const bool valid = (in_y >= 0.0f) & (in_y <= (float)(IMG_H - 1)) &
                       (in_x >= 0.0f) & (in_x <= (float)(IMG_W - 1));
    const float yc = fminf(fmaxf(in_y, 0.0f), (float)(IMG_H - 1));
    const float xc = fminf(fmaxf(in_x, 0.0f), (float)(IMG_W - 1));
    const float y0f = floorf(yc), x0f = floorf(xc);
    const float ly = yc - y0f, lx = xc - x0f;
    const int y0 = (int)y0f, x0 = (int)x0f;
    const int y1i = min(y0 + 1, IMG_H - 1), x1i = min(x0 + 1, IMG_W - 1);

    const float* __restrict__ p = image + ((size_t)(b * NCH + c)) * PLANE;
    const float tl = p[y0  * IMG_W + x0];
    const float tr = p[y0  * IMG_W + x1i];
    const float bl = p[y1i * IMG_W + x0];
    const float br = p[y1i * IMG_W + x1i];
    const float top = tl + (tr - tl) * lx;
    const float bot = bl + (br - bl) * lx;
    float val = top + (bot - top) * ly;
    out[(size_t)n * (NCH * CROP_HW) + i] = valid ? val : 0.0f;
}

extern "C" void kernel_launch(void* const* d_in, const int* in_sizes, int n_in,
                              void* d_out, int out_size, void* d_ws, size_t ws_size,
                              hipStream_t stream) {
    const float* image   = (const float*)d_in[0];
    const float* boxes   = (const float*)d_in[1];
    const int*   box_ind = (const int*)d_in[2];
    float* out = (float*)d_out;

    if (ws_size < WS_NEED) {
        dim3 grid(196, NBOX);
        crop_resize_simple<<<grid, dim3(256), 0, stream>>>(image, boxes, box_ind, out);
        return;
    }

    uint2* geo = (uint2*)d_ws;

    geom_kernel<<<dim3(NBOX), dim3(256), 0, stream>>>(boxes, box_ind, geo);
    crop_resize_main<<<dim3(NIMG * NCH), dim3(512), 0, stream>>>(image, box_ind, geo, out);
}